// Round 1
// baseline (461.773 us; speedup 1.0000x reference)
//
#include <hip/hip_runtime.h>
#include <math.h>

// ONNX_TRT_MASK2: detection mask head post-processing.
// Dead inputs: x0 (scores never returned), bases. Real work:
//   det_attn = attn[b, det_indices[b,m], :]  (980 floats = 5x14x14)
//   bilinear 14->56 (half-pixel centers, edge clamp), softmax over 5,
//   masks = sigmoid(sum_c pooled[c] * softmax_c)
// Output flat: num_det(4) | det_boxes(1600) | det_scores(400) |
//              det_classes(400) | masks(400*3136)   -- all as float32.

namespace {
constexpr int kB       = 4;
constexpr int kN       = 25200;
constexpr int kMax     = 100;
constexpr int kNB      = 5;
constexpr int kAR      = 14;
constexpr int kMR      = 56;
constexpr int kAttnRow = kNB * kAR * kAR;      // 980
constexpr int kMaskPix = kMR * kMR;            // 3136
constexpr int kQuads   = kMaskPix / 4;         // 784
constexpr int kHdrBoxes   = kB;                            // 4
constexpr int kHdrScores  = kHdrBoxes + kB * kMax * 4;     // 1604
constexpr int kHdrClasses = kHdrScores + kB * kMax;        // 2004
constexpr int kHdr        = kHdrClasses + kB * kMax;       // 2404
constexpr int kSplit   = 2;    // blocks per detection (parallelism: 801 blocks)
constexpr int kThreads = 256;
}

__global__ __launch_bounds__(kThreads)
void mask_kernel(const float* __restrict__ attn,
                 const int*   __restrict__ num_det,
                 const float* __restrict__ det_boxes,
                 const float* __restrict__ det_scores,
                 const int*   __restrict__ det_classes,
                 const int*   __restrict__ det_indices,
                 const float* __restrict__ pooled,
                 float*       __restrict__ out)
{
    const int blk = blockIdx.x;

    // Tail block: copy pass-through outputs (ints widened to float).
    if (blk >= kB * kMax * kSplit) {
        for (int i = threadIdx.x; i < kHdr; i += kThreads) {
            float v;
            if (i < kHdrBoxes)        v = (float)num_det[i];
            else if (i < kHdrScores)  v = det_boxes[i - kHdrBoxes];
            else if (i < kHdrClasses) v = det_scores[i - kHdrScores];
            else                      v = (float)det_classes[i - kHdrClasses];
            out[i] = v;
        }
        return;
    }

    const int det  = blk / kSplit;
    const int part = blk % kSplit;
    const int b    = det / kMax;
    const int m    = det % kMax;

    // Stage this detection's 980-float attn row in LDS (float4 coalesced).
    __shared__ float s[kAttnRow];
    {
        const int idx = det_indices[b * kMax + m];
        const float4* src =
            reinterpret_cast<const float4*>(attn + ((long)b * kN + idx) * kAttnRow);
        float4* dst = reinterpret_cast<float4*>(s);
        if (threadIdx.x < kAttnRow / 4) dst[threadIdx.x] = src[threadIdx.x];
    }
    __syncthreads();

    const float* pb = pooled + (long)det * kNB * kMaskPix;
    float*       ob = out + kHdr + (long)det * kMaskPix;

    // Each thread owns 4 consecutive pixels (same output row; 56 % 4 == 0).
    for (int q = part * kThreads + threadIdx.x; q < kQuads; q += kSplit * kThreads) {
        const int p0 = q * 4;
        const int y  = p0 / kMR;
        const int xb = p0 % kMR;

        // jax.image.resize bilinear: src coord = 0.25*i - 0.375, edge clamp.
        const float fy = 0.25f * (float)y - 0.375f;
        const int   y0 = (int)floorf(fy);
        const float wy = fy - (float)y0;
        const int y0c = max(y0, 0) * kAR;
        const int y1c = min(y0 + 1, kAR - 1) * kAR;

        float4 pv[kNB];
        #pragma unroll
        for (int c = 0; c < kNB; ++c)
            pv[c] = reinterpret_cast<const float4*>(pb + c * kMaskPix + p0)[0];

        float res[4];
        #pragma unroll
        for (int k = 0; k < 4; ++k) {
            const int   x  = xb + k;
            const float fx = 0.25f * (float)x - 0.375f;
            const int   x0 = (int)floorf(fx);
            const float wx = fx - (float)x0;
            const int x0c = max(x0, 0);
            const int x1c = min(x0 + 1, kAR - 1);

            float v[kNB];
            float vmax = -INFINITY;
            #pragma unroll
            for (int c = 0; c < kNB; ++c) {
                const float* sc  = s + c * kAR * kAR;
                const float a00 = sc[y0c + x0c];
                const float a01 = sc[y0c + x1c];
                const float a10 = sc[y1c + x0c];
                const float a11 = sc[y1c + x1c];
                const float top = a00 + wx * (a01 - a00);
                const float bot = a10 + wx * (a11 - a10);
                v[c] = top + wy * (bot - top);
                vmax = fmaxf(vmax, v[c]);
            }
            float esum = 0.0f, acc = 0.0f;
            #pragma unroll
            for (int c = 0; c < kNB; ++c) {
                const float e = __expf(v[c] - vmax);
                esum += e;
                acc  += ((const float*)&pv[c])[k] * e;
            }
            acc /= esum;
            res[k] = 1.0f / (1.0f + __expf(-acc));
        }
        reinterpret_cast<float4*>(ob + p0)[0] =
            make_float4(res[0], res[1], res[2], res[3]);
    }
}

extern "C" void kernel_launch(void* const* d_in, const int* in_sizes, int n_in,
                              void* d_out, int out_size, void* d_ws, size_t ws_size,
                              hipStream_t stream) {
    // setup_inputs order: x0, attn, bases, num_det, det_boxes, det_scores,
    //                     det_classes, det_indices, pooled_bases
    const float* attn        = (const float*)d_in[1];
    const int*   num_det     = (const int*)  d_in[3];
    const float* det_boxes   = (const float*)d_in[4];
    const float* det_scores  = (const float*)d_in[5];
    const int*   det_classes = (const int*)  d_in[6];
    const int*   det_indices = (const int*)  d_in[7];
    const float* pooled      = (const float*)d_in[8];
    float*       out         = (float*)d_out;

    mask_kernel<<<kB * kMax * kSplit + 1, kThreads, 0, stream>>>(
        attn, num_det, det_boxes, det_scores, det_classes, det_indices,
        pooled, out);
}

// Round 2
// 461.688 us; speedup vs baseline: 1.0002x; 1.0002x over previous
//
#include <hip/hip_runtime.h>
#include <math.h>

// ONNX_TRT_MASK2: detection mask head post-processing.
// Dead inputs: x0 (conf/scores never returned), bases. Real work:
//   det_attn = attn[b, det_indices[b,m], :]  (980 floats = 5x14x14)
//   bilinear 14->56 (half-pixel centers, edge clamp), softmax over NB=5,
//   masks = sigmoid(sum_c pooled[c] * softmax_c)
// Output flat: num_det(4) | det_boxes(1600) | det_scores(400) |
//              det_classes(400) | masks(400*3136)   -- all as float32.
//
// R1 note: measured 461 us is dominated by harness re-poison of the 1.58 GB
// d_ws (rocprof top-5 = fillBufferAligned, 250 us each) + input restore.
// Kernel's own traffic is ~33 MB (~6 us at HBM ceiling).

namespace {
constexpr int kB       = 4;
constexpr int kN       = 25200;
constexpr int kMax     = 100;
constexpr int kNB      = 5;
constexpr int kAR      = 14;
constexpr int kMR      = 56;
constexpr int kAttnRow = kNB * kAR * kAR;      // 980
constexpr int kMaskPix = kMR * kMR;            // 3136
constexpr int kQuads   = kMaskPix / 4;         // 784
constexpr int kHdrBoxes   = kB;                            // 4
constexpr int kHdrScores  = kHdrBoxes + kB * kMax * 4;     // 1604
constexpr int kHdrClasses = kHdrScores + kB * kMax;        // 2004
constexpr int kHdr        = kHdrClasses + kB * kMax;       // 2404
constexpr int kSplit     = 4;                  // blocks per detection
constexpr int kQPerPart  = kQuads / kSplit;    // 196 quads = 14 mask rows
constexpr int kThreads   = 256;
}

__global__ __launch_bounds__(kThreads)
void mask_kernel(const float* __restrict__ attn,
                 const int*   __restrict__ num_det,
                 const float* __restrict__ det_boxes,
                 const float* __restrict__ det_scores,
                 const int*   __restrict__ det_classes,
                 const int*   __restrict__ det_indices,
                 const float* __restrict__ pooled,
                 float*       __restrict__ out)
{
    const int blk = blockIdx.x;

    // Tail block: copy pass-through outputs (ints widened to float).
    if (blk >= kB * kMax * kSplit) {
        for (int i = threadIdx.x; i < kHdr; i += kThreads) {
            float v;
            if (i < kHdrBoxes)        v = (float)num_det[i];
            else if (i < kHdrScores)  v = det_boxes[i - kHdrBoxes];
            else if (i < kHdrClasses) v = det_scores[i - kHdrScores];
            else                      v = (float)det_classes[i - kHdrClasses];
            out[i] = v;
        }
        return;
    }

    const int det  = blk / kSplit;
    const int part = blk % kSplit;
    const int b    = det / kMax;
    const int m    = det % kMax;

    // Stage this detection's 980-float attn row in LDS (float4 coalesced).
    __shared__ float s[kAttnRow];
    {
        const int idx = det_indices[b * kMax + m];
        const float4* src =
            reinterpret_cast<const float4*>(attn + ((long)b * kN + idx) * kAttnRow);
        float4* dst = reinterpret_cast<float4*>(s);
        if (threadIdx.x < kAttnRow / 4) dst[threadIdx.x] = src[threadIdx.x];
    }
    __syncthreads();

    if (threadIdx.x >= kQPerPart) return;   // 196 active threads, 1 quad each

    const float* pb = pooled + (long)det * kNB * kMaskPix;
    float*       ob = out + kHdr + (long)det * kMaskPix;

    const int q  = part * kQPerPart + threadIdx.x;  // contiguous chunk per part
    const int p0 = q * 4;
    const int y  = p0 / kMR;
    const int xb = p0 % kMR;

    // jax.image.resize bilinear: src coord = 0.25*i - 0.375, edge clamp.
    const float fy = 0.25f * (float)y - 0.375f;
    const int   y0 = (int)floorf(fy);
    const float wy = fy - (float)y0;
    const int y0c = max(y0, 0) * kAR;
    const int y1c = min(y0 + 1, kAR - 1) * kAR;

    float4 pv[kNB];
    #pragma unroll
    for (int c = 0; c < kNB; ++c)
        pv[c] = reinterpret_cast<const float4*>(pb + c * kMaskPix + p0)[0];

    float res[4];
    #pragma unroll
    for (int k = 0; k < 4; ++k) {
        const int   x  = xb + k;
        const float fx = 0.25f * (float)x - 0.375f;
        const int   x0 = (int)floorf(fx);
        const float wx = fx - (float)x0;
        const int x0c = max(x0, 0);
        const int x1c = min(x0 + 1, kAR - 1);

        float v[kNB];
        float vmax = -INFINITY;
        #pragma unroll
        for (int c = 0; c < kNB; ++c) {
            const float* sc  = s + c * kAR * kAR;
            const float a00 = sc[y0c + x0c];
            const float a01 = sc[y0c + x1c];
            const float a10 = sc[y1c + x0c];
            const float a11 = sc[y1c + x1c];
            const float top = a00 + wx * (a01 - a00);
            const float bot = a10 + wx * (a11 - a10);
            v[c] = top + wy * (bot - top);
            vmax = fmaxf(vmax, v[c]);
        }
        float esum = 0.0f, acc = 0.0f;
        #pragma unroll
        for (int c = 0; c < kNB; ++c) {
            const float e = __expf(v[c] - vmax);
            esum += e;
            acc  += ((const float*)&pv[c])[k] * e;
        }
        acc /= esum;
        res[k] = 1.0f / (1.0f + __expf(-acc));
    }
    reinterpret_cast<float4*>(ob + p0)[0] =
        make_float4(res[0], res[1], res[2], res[3]);
}

extern "C" void kernel_launch(void* const* d_in, const int* in_sizes, int n_in,
                              void* d_out, int out_size, void* d_ws, size_t ws_size,
                              hipStream_t stream) {
    // setup_inputs order: x0, attn, bases, num_det, det_boxes, det_scores,
    //                     det_classes, det_indices, pooled_bases
    const float* attn        = (const float*)d_in[1];
    const int*   num_det     = (const int*)  d_in[3];
    const float* det_boxes   = (const float*)d_in[4];
    const float* det_scores  = (const float*)d_in[5];
    const int*   det_classes = (const int*)  d_in[6];
    const int*   det_indices = (const int*)  d_in[7];
    const float* pooled      = (const float*)d_in[8];
    float*       out         = (float*)d_out;

    mask_kernel<<<kB * kMax * kSplit + 1, kThreads, 0, stream>>>(
        attn, num_det, det_boxes, det_scores, det_classes, det_indices,
        pooled, out);
}